// Round 1
// baseline (927.052 us; speedup 1.0000x reference)
//
#include <hip/hip_runtime.h>
#include <hip/hip_bf16.h>
#include <math.h>

#define CDIM  50257
#define BDIM  2048
#define TK    100
#define INTER 256
#define CIN   200
#define NBINS 4096
#define CAP   4096
#define BNEPS 1e-5f

__device__ __forceinline__ unsigned int ordered_bits(float x) {
    unsigned int u = __float_as_uint(x);
    return (u & 0x80000000u) ? ~u : (u | 0x80000000u);
}

// ---------------- kernel 0: transpose conv1_w [256][200] -> w1t [200][256] ----------------
__global__ __launch_bounds__(256) void transpose_w1(const float* __restrict__ w1,
                                                    float* __restrict__ w1t) {
    int o = blockIdx.x * 256 + threadIdx.x;
    if (o < INTER * CIN) {
        int c = o & (INTER - 1);   // output channel
        int k = o >> 8;            // input feature
        w1t[o] = w1[c * CIN + k];
    }
}

// ---------------- kernel 1: per-row softmax/top-k/gather + conv1 ----------------
__global__ __launch_bounds__(256) void row_kernel(const float* __restrict__ tea,
                                                  const float* __restrict__ stu,
                                                  const float* __restrict__ w1t,
                                                  const float* __restrict__ bias1,
                                                  float* __restrict__ h) {
    __shared__ unsigned int hist[NBINS];
    __shared__ float        cand_x[CAP];
    __shared__ int          cand_i[CAP];
    __shared__ unsigned int chunk[256];
    __shared__ float        comb[CIN];     // [0..99] teacher topk p, [100..199] student p
    __shared__ int          sel_idx[TK];
    __shared__ float        red_a[4], red_b[4];
    __shared__ int          s_bin1;
    __shared__ unsigned int cand_cnt;

    const int tid = threadIdx.x;
    const int row = blockIdx.x;
    const float* trow = tea + (size_t)row * CDIM;
    const float* srow = stu + (size_t)row * CDIM;

    for (int i = tid; i < NBINS; i += 256) hist[i] = 0u;
    if (tid == 0) cand_cnt = 0u;
    __syncthreads();

    // ---- pass 1 over teacher: row max + histogram of top-12 ordered bits ----
    float m = -INFINITY;
    for (int i = tid; i < CDIM; i += 256) {
        float x = trow[i];
        m = fmaxf(m, x);
        atomicAdd(&hist[ordered_bits(x) >> 20], 1u);
    }
#pragma unroll
    for (int o = 32; o; o >>= 1) m = fmaxf(m, __shfl_xor(m, o, 64));
    if ((tid & 63) == 0) red_a[tid >> 6] = m;
    __syncthreads();
    const float M = fmaxf(fmaxf(red_a[0], red_a[1]), fmaxf(red_a[2], red_a[3]));

    // ---- boundary bin: smallest bin b such that count(bins > b) < K <= count(bins >= b) ----
    unsigned int cs = 0;
#pragma unroll
    for (int i = 0; i < NBINS / 256; ++i) cs += hist[tid * (NBINS / 256) + i];
    chunk[tid] = cs;
    __syncthreads();
    if (tid == 0) {
        unsigned int acc = 0;
        int t = 255;
        for (; t > 0; --t) {
            if (acc + chunk[t] >= TK) break;
            acc += chunk[t];
        }
        int b = t * 16;
        for (int i = 15; i >= 0; --i) {
            unsigned int hv = hist[t * 16 + i];
            if (acc + hv >= TK) { b = t * 16 + i; break; }
            acc += hv;
        }
        s_bin1 = b;
    }
    __syncthreads();
    const unsigned int bin1 = (unsigned int)s_bin1;

    // ---- pass 2 over teacher: exp-sum + collect candidates (bins >= bin1) ----
    float s = 0.f;
    for (int i = tid; i < CDIM; i += 256) {
        float x = trow[i];
        s += expf(x - M);
        if ((ordered_bits(x) >> 20) >= bin1) {
            unsigned int pos = atomicAdd(&cand_cnt, 1u);
            if (pos < CAP) { cand_x[pos] = x; cand_i[pos] = i; }
        }
    }
#pragma unroll
    for (int o = 32; o; o >>= 1) s += __shfl_xor(s, o, 64);
    if ((tid & 63) == 0) red_b[tid >> 6] = s;
    __syncthreads();
    const float S = (red_b[0] + red_b[1]) + (red_b[2] + red_b[3]);

    int n = (int)cand_cnt; if (n > CAP) n = CAP;

    // candidates -> softmax probabilities (reference compares these)
    for (int i = tid; i < n; i += 256) cand_x[i] = expf(cand_x[i] - M) / S;
    __syncthreads();

    // exact rank among candidates: descending p, ties -> lower index first
    for (int i = tid; i < n; i += 256) {
        float pi = cand_x[i];
        int   ii = cand_i[i];
        int r = 0;
        for (int j = 0; j < n; ++j) {
            float pj = cand_x[j];
            r += (pj > pi) || ((pj == pi) && (cand_i[j] < ii));
        }
        if (r < TK) { comb[r] = pi; sel_idx[r] = ii; }
    }

    // ---- student: single-pass online softmax (max + sum) ----
    float m2 = -INFINITY, s2 = 0.f;
    for (int i = tid; i < CDIM; i += 256) {
        float x = srow[i];
        if (x > m2) { s2 = s2 * expf(m2 - x) + 1.f; m2 = x; }
        else        { s2 += expf(x - m2); }
    }
#pragma unroll
    for (int o = 32; o; o >>= 1) {
        float mo = __shfl_xor(m2, o, 64);
        float so = __shfl_xor(s2, o, 64);
        float mn = fmaxf(m2, mo);
        s2 = s2 * expf(m2 - mn) + so * expf(mo - mn);
        m2 = mn;
    }
    __syncthreads();   // red_a/red_b reuse; also fences sel_idx/comb writes
    if ((tid & 63) == 0) { red_a[tid >> 6] = m2; red_b[tid >> 6] = s2; }
    __syncthreads();
    float M2 = red_a[0], S2 = red_b[0];
#pragma unroll
    for (int w = 1; w < 4; ++w) {
        float mn = fmaxf(M2, red_a[w]);
        S2 = S2 * expf(M2 - mn) + red_b[w] * expf(red_a[w] - mn);
        M2 = mn;
    }

    // gather student probs at teacher's top-k indices
    if (tid < TK) {
        float xg = srow[sel_idx[tid]];
        comb[TK + tid] = expf(xg - M2) / S2;
    }
    __syncthreads();

    // ---- conv1: h[row][c] = bias1[c] + sum_k comb[k] * w1t[k][c] ----
    float hc = bias1[tid];
#pragma unroll 4
    for (int k = 0; k < CIN; ++k) hc = fmaf(comb[k], w1t[k * INTER + tid], hc);
    h[(size_t)row * INTER + tid] = hc;
}

// ---------------- kernel 2: batch-norm statistics (mean + biased var per column) ----------------
__global__ __launch_bounds__(256) void bn_stats(const float* __restrict__ h,
                                                float* __restrict__ mv) {
    const int c = blockIdx.x, tid = threadIdx.x;
    __shared__ float red[4];
    float v[BDIM / 256];
    float s = 0.f;
#pragma unroll
    for (int r = 0; r < BDIM / 256; ++r) {
        v[r] = h[(size_t)(r * 256 + tid) * INTER + c];
        s += v[r];
    }
#pragma unroll
    for (int o = 32; o; o >>= 1) s += __shfl_xor(s, o, 64);
    if ((tid & 63) == 0) red[tid >> 6] = s;
    __syncthreads();
    const float mu = ((red[0] + red[1]) + (red[2] + red[3])) * (1.f / BDIM);
    __syncthreads();
    float q = 0.f;
#pragma unroll
    for (int r = 0; r < BDIM / 256; ++r) { float d = v[r] - mu; q = fmaf(d, d, q); }
#pragma unroll
    for (int o = 32; o; o >>= 1) q += __shfl_xor(q, o, 64);
    if ((tid & 63) == 0) red[tid >> 6] = q;
    __syncthreads();
    if (tid == 0) {
        mv[c]         = mu;
        mv[INTER + c] = ((red[0] + red[1]) + (red[2] + red[3])) * (1.f / BDIM);
    }
}

// ---------------- kernel 3: BN apply + ReLU + conv2 -> out[row] ----------------
__global__ __launch_bounds__(256) void bn_out(const float* __restrict__ h,
                                              const float* __restrict__ mv,
                                              const float* __restrict__ gamma,
                                              const float* __restrict__ beta,
                                              const float* __restrict__ w2,
                                              const float* __restrict__ b2,
                                              float* __restrict__ out) {
    const int r = blockIdx.x, c = threadIdx.x;
    __shared__ float red[4];
    const float mu  = mv[c];
    const float var = mv[INTER + c];
    const float rs  = 1.0f / sqrtf(var + BNEPS);
    float hv = h[(size_t)r * INTER + c];
    float hn = gamma[c] * (hv - mu) * rs + beta[c];
    hn = fmaxf(hn, 0.f);
    float term = hn * w2[c];
#pragma unroll
    for (int o = 32; o; o >>= 1) term += __shfl_xor(term, o, 64);
    if ((c & 63) == 0) red[c >> 6] = term;
    __syncthreads();
    if (c == 0) out[r] = ((red[0] + red[1]) + (red[2] + red[3])) + b2[0];
}

extern "C" void kernel_launch(void* const* d_in, const int* in_sizes, int n_in,
                              void* d_out, int out_size, void* d_ws, size_t ws_size,
                              hipStream_t stream) {
    const float* tea   = (const float*)d_in[0];
    const float* stu   = (const float*)d_in[1];
    // d_in[2] = lambda_, unused in forward (gradient reversal is identity)
    const float* w1    = (const float*)d_in[3];
    const float* bias1 = (const float*)d_in[4];
    const float* gamma = (const float*)d_in[5];
    const float* beta  = (const float*)d_in[6];
    const float* w2    = (const float*)d_in[7];
    const float* b2    = (const float*)d_in[8];
    float* out = (float*)d_out;

    char* ws = (char*)d_ws;
    float* h   = (float*)ws;                                            // 2048*256 f32
    float* w1t = (float*)(ws + (size_t)BDIM * INTER * sizeof(float));   // 200*256 f32
    float* mv  = (float*)(ws + (size_t)BDIM * INTER * sizeof(float)
                             + (size_t)CIN * INTER * sizeof(float));    // 2*256 f32

    transpose_w1<<<(INTER * CIN + 255) / 256, 256, 0, stream>>>(w1, w1t);
    row_kernel<<<BDIM, 256, 0, stream>>>(tea, stu, w1t, bias1, h);
    bn_stats<<<INTER, 256, 0, stream>>>(h, mv);
    bn_out<<<BDIM, 256, 0, stream>>>(h, mv, gamma, beta, w2, b2, out);
}

// Round 2
// 231.945 us; speedup vs baseline: 3.9969x; 3.9969x over previous
//
#include <hip/hip_runtime.h>
#include <hip/hip_bf16.h>
#include <math.h>

#define CDIM  50257
#define BDIM  2048
#define TK    100
#define INTER 256
#define CIN   200
#define NBINS 4096
#define CAP   2048
#define BNEPS 1e-5f

typedef float f32x4 __attribute__((ext_vector_type(4)));

__device__ __forceinline__ unsigned int ordered_bits(float x) {
    unsigned int u = __float_as_uint(x);
    return (u & 0x80000000u) ? ~u : (u | 0x80000000u);
}
// inverse of ordered_bits (monotone bijection)
__device__ __forceinline__ float inv_ordered(unsigned int o) {
    unsigned int u = (o & 0x80000000u) ? (o & 0x7fffffffu) : ~o;
    return __uint_as_float(u);
}

__device__ __forceinline__ void online1(float x, float& m, float& s) {
    if (x > m) { s = s * __expf(m - x) + 1.f; m = x; }
    else       { s += __expf(x - m); }
}
__device__ __forceinline__ void online4(f32x4 v, float& m, float& s) {
    float m4 = fmaxf(fmaxf(v.x, v.y), fmaxf(v.z, v.w));
    if (m4 > m) { s *= __expf(m - m4); m = m4; }
    s += __expf(v.x - m) + __expf(v.y - m) + __expf(v.z - m) + __expf(v.w - m);
}

// ---------------- kernel 0: transpose conv1_w [256][200] -> w1t [200][256] ----------------
__global__ __launch_bounds__(256) void transpose_w1(const float* __restrict__ w1,
                                                    float* __restrict__ w1t) {
    int o = blockIdx.x * 256 + threadIdx.x;
    if (o < INTER * CIN) {
        int c = o & (INTER - 1);
        int k = o >> 8;
        w1t[o] = w1[c * CIN + k];
    }
}

// ---------------- kernel 1: per-row softmax/top-k/gather + conv1 ----------------
__global__ __launch_bounds__(256, 8) void row_kernel(const float* __restrict__ tea,
                                                     const float* __restrict__ stu,
                                                     const float* __restrict__ w1t,
                                                     const float* __restrict__ bias1,
                                                     float* __restrict__ h) {
    // hist (16KB) is dead after bin1 is known -> reuse the same pool for candidates
    __shared__ __align__(16) unsigned char pool[NBINS * 4];
    unsigned int* hist   = (unsigned int*)pool;
    float*        cand_x = (float*)pool;                      // CAP floats (8KB)
    int*          cand_i = (int*)(pool + CAP * sizeof(float)); // CAP ints   (8KB)
    __shared__ unsigned int chunk[256];
    __shared__ float comb[CIN];
    __shared__ int   sel_idx[TK];
    __shared__ float red_a[4], red_b[4];
    __shared__ int   s_bin1;
    __shared__ unsigned int cand_cnt;

    const int tid = threadIdx.x;
    const int row = blockIdx.x;
    const float* trow = tea + (size_t)row * CDIM;
    const float* srow = stu + (size_t)row * CDIM;

    // alignment split: rows start at (row&3)*4 bytes mod 16
    const int pre  = (4 - (row & 3)) & 3;
    const int nv   = (CDIM - pre) >> 2;
    const int tail = pre + (nv << 2);
    const f32x4* tv4 = (const f32x4*)(trow + pre);
    const f32x4* sv4 = (const f32x4*)(srow + pre);

    for (int i = tid; i < NBINS; i += 256) hist[i] = 0u;
    if (tid == 0) cand_cnt = 0u;
    __syncthreads();

    // ---- pass 1 over teacher: histogram + online softmax (max+sum fused) ----
    float m = -INFINITY, s = 0.f;
    for (int i = tid; i < pre; i += 256) {
        float x = trow[i];
        atomicAdd(&hist[ordered_bits(x) >> 20], 1u);
        online1(x, m, s);
    }
    for (int i = tail + tid; i < CDIM; i += 256) {
        float x = trow[i];
        atomicAdd(&hist[ordered_bits(x) >> 20], 1u);
        online1(x, m, s);
    }
    for (int k = tid; k < nv; k += 256) {
        f32x4 v = tv4[k];
        atomicAdd(&hist[ordered_bits(v.x) >> 20], 1u);
        atomicAdd(&hist[ordered_bits(v.y) >> 20], 1u);
        atomicAdd(&hist[ordered_bits(v.z) >> 20], 1u);
        atomicAdd(&hist[ordered_bits(v.w) >> 20], 1u);
        online4(v, m, s);
    }
#pragma unroll
    for (int o = 32; o; o >>= 1) {
        float mo = __shfl_xor(m, o, 64), so = __shfl_xor(s, o, 64);
        float mn = fmaxf(m, mo);
        s = s * __expf(m - mn) + so * __expf(mo - mn);
        m = mn;
    }
    if ((tid & 63) == 0) { red_a[tid >> 6] = m; red_b[tid >> 6] = s; }
    __syncthreads();                    // hist complete + red written
    float M = red_a[0], S = red_b[0];
#pragma unroll
    for (int w = 1; w < 4; ++w) {
        float mn = fmaxf(M, red_a[w]);
        S = S * __expf(M - mn) + red_b[w] * __expf(red_a[w] - mn);
        M = mn;
    }

    // ---- boundary bin for top-K ----
    unsigned int cs = 0;
#pragma unroll
    for (int i = 0; i < NBINS / 256; ++i) cs += hist[tid * (NBINS / 256) + i];
    chunk[tid] = cs;
    __syncthreads();
    if (tid == 0) {
        unsigned int acc = 0;
        int t = 255;
        for (; t > 0; --t) {
            if (acc + chunk[t] >= TK) break;
            acc += chunk[t];
        }
        int b = t * 16;
        for (int i = 15; i >= 0; --i) {
            unsigned int hv = hist[t * 16 + i];
            if (acc + hv >= TK) { b = t * 16 + i; break; }
            acc += hv;
        }
        s_bin1 = b;
    }
    __syncthreads();
    // float-domain threshold equivalent to (ordered_bits(x)>>20) >= bin1
    const float thr = inv_ordered(((unsigned int)s_bin1) << 20);
    // pool is now reused as cand_x/cand_i (hist no longer read past this point)

    // ---- pass 2 over teacher: collect-only (1 cmp/elem), non-temporal ----
    for (int i = tid; i < pre; i += 256) {
        float x = trow[i];
        if (x >= thr) { unsigned p = atomicAdd(&cand_cnt, 1u); if (p < CAP) { cand_x[p] = x; cand_i[p] = i; } }
    }
    for (int i = tail + tid; i < CDIM; i += 256) {
        float x = trow[i];
        if (x >= thr) { unsigned p = atomicAdd(&cand_cnt, 1u); if (p < CAP) { cand_x[p] = x; cand_i[p] = i; } }
    }
    for (int k = tid; k < nv; k += 256) {
        f32x4 v = __builtin_nontemporal_load(tv4 + k);
        int base = pre + 4 * k;
        if (v.x >= thr) { unsigned p = atomicAdd(&cand_cnt, 1u); if (p < CAP) { cand_x[p] = v.x; cand_i[p] = base; } }
        if (v.y >= thr) { unsigned p = atomicAdd(&cand_cnt, 1u); if (p < CAP) { cand_x[p] = v.y; cand_i[p] = base + 1; } }
        if (v.z >= thr) { unsigned p = atomicAdd(&cand_cnt, 1u); if (p < CAP) { cand_x[p] = v.z; cand_i[p] = base + 2; } }
        if (v.w >= thr) { unsigned p = atomicAdd(&cand_cnt, 1u); if (p < CAP) { cand_x[p] = v.w; cand_i[p] = base + 3; } }
    }
    __syncthreads();
    int n = (int)cand_cnt; if (n > CAP) n = CAP;

    // candidates -> softmax probabilities (reference compares these)
    for (int i = tid; i < n; i += 256) cand_x[i] = __expf(cand_x[i] - M) / S;
    __syncthreads();

    // exact rank among candidates: descending p, ties -> lower index first
    for (int i = tid; i < n; i += 256) {
        float pi = cand_x[i];
        int   ii = cand_i[i];
        int r = 0;
        for (int j = 0; j < n; ++j) {
            float pj = cand_x[j];
            r += (pj > pi) || ((pj == pi) && (cand_i[j] < ii));
        }
        if (r < TK) { comb[r] = pi; sel_idx[r] = ii; }
    }

    // ---- student: single-pass online softmax, non-temporal ----
    float m2 = -INFINITY, s2 = 0.f;
    for (int i = tid; i < pre; i += 256)        online1(srow[i], m2, s2);
    for (int i = tail + tid; i < CDIM; i += 256) online1(srow[i], m2, s2);
    for (int k = tid; k < nv; k += 256) {
        f32x4 v = __builtin_nontemporal_load(sv4 + k);
        online4(v, m2, s2);
    }
#pragma unroll
    for (int o = 32; o; o >>= 1) {
        float mo = __shfl_xor(m2, o, 64), so = __shfl_xor(s2, o, 64);
        float mn = fmaxf(m2, mo);
        s2 = s2 * __expf(m2 - mn) + so * __expf(mo - mn);
        m2 = mn;
    }
    __syncthreads();   // ranking writes (comb/sel_idx) complete; red_a/red_b free
    if ((tid & 63) == 0) { red_a[tid >> 6] = m2; red_b[tid >> 6] = s2; }
    __syncthreads();
    float M2 = red_a[0], S2 = red_b[0];
#pragma unroll
    for (int w = 1; w < 4; ++w) {
        float mn = fmaxf(M2, red_a[w]);
        S2 = S2 * __expf(M2 - mn) + red_b[w] * __expf(red_a[w] - mn);
        M2 = mn;
    }

    // gather student probs at teacher's top-k indices
    if (tid < TK) {
        float xg = srow[sel_idx[tid]];
        comb[TK + tid] = __expf(xg - M2) / S2;
    }
    __syncthreads();

    // ---- conv1: h[row][c] = bias1[c] + sum_k comb[k] * w1t[k][c] ----
    float hc = bias1[tid];
#pragma unroll 4
    for (int k = 0; k < CIN; ++k) hc = fmaf(comb[k], w1t[k * INTER + tid], hc);
    h[(size_t)row * INTER + tid] = hc;
}

// ---------------- kernel 2: batch-norm statistics (mean + biased var per column) ----------------
__global__ __launch_bounds__(256) void bn_stats(const float* __restrict__ h,
                                                float* __restrict__ mv) {
    const int c = blockIdx.x, tid = threadIdx.x;
    __shared__ float red[4];
    float v[BDIM / 256];
    float s = 0.f;
#pragma unroll
    for (int r = 0; r < BDIM / 256; ++r) {
        v[r] = h[(size_t)(r * 256 + tid) * INTER + c];
        s += v[r];
    }
#pragma unroll
    for (int o = 32; o; o >>= 1) s += __shfl_xor(s, o, 64);
    if ((tid & 63) == 0) red[tid >> 6] = s;
    __syncthreads();
    const float mu = ((red[0] + red[1]) + (red[2] + red[3])) * (1.f / BDIM);
    __syncthreads();
    float q = 0.f;
#pragma unroll
    for (int r = 0; r < BDIM / 256; ++r) { float d = v[r] - mu; q = fmaf(d, d, q); }
#pragma unroll
    for (int o = 32; o; o >>= 1) q += __shfl_xor(q, o, 64);
    if ((tid & 63) == 0) red[tid >> 6] = q;
    __syncthreads();
    if (tid == 0) {
        mv[c]         = mu;
        mv[INTER + c] = ((red[0] + red[1]) + (red[2] + red[3])) * (1.f / BDIM);
    }
}

// ---------------- kernel 3: BN apply + ReLU + conv2 -> out[row] ----------------
__global__ __launch_bounds__(256) void bn_out(const float* __restrict__ h,
                                              const float* __restrict__ mv,
                                              const float* __restrict__ gamma,
                                              const float* __restrict__ beta,
                                              const float* __restrict__ w2,
                                              const float* __restrict__ b2,
                                              float* __restrict__ out) {
    const int r = blockIdx.x, c = threadIdx.x;
    __shared__ float red[4];
    const float mu  = mv[c];
    const float var = mv[INTER + c];
    const float rs  = 1.0f / sqrtf(var + BNEPS);
    float hv = h[(size_t)r * INTER + c];
    float hn = gamma[c] * (hv - mu) * rs + beta[c];
    hn = fmaxf(hn, 0.f);
    float term = hn * w2[c];
#pragma unroll
    for (int o = 32; o; o >>= 1) term += __shfl_xor(term, o, 64);
    if ((c & 63) == 0) red[c >> 6] = term;
    __syncthreads();
    if (c == 0) out[r] = ((red[0] + red[1]) + (red[2] + red[3])) + b2[0];
}

extern "C" void kernel_launch(void* const* d_in, const int* in_sizes, int n_in,
                              void* d_out, int out_size, void* d_ws, size_t ws_size,
                              hipStream_t stream) {
    const float* tea   = (const float*)d_in[0];
    const float* stu   = (const float*)d_in[1];
    // d_in[2] = lambda_, unused in forward (gradient reversal is identity)
    const float* w1    = (const float*)d_in[3];
    const float* bias1 = (const float*)d_in[4];
    const float* gamma = (const float*)d_in[5];
    const float* beta  = (const float*)d_in[6];
    const float* w2    = (const float*)d_in[7];
    const float* b2    = (const float*)d_in[8];
    float* out = (float*)d_out;

    char* ws = (char*)d_ws;
    float* h   = (float*)ws;                                            // 2048*256 f32
    float* w1t = (float*)(ws + (size_t)BDIM * INTER * sizeof(float));   // 200*256 f32
    float* mv  = (float*)(ws + (size_t)BDIM * INTER * sizeof(float)
                             + (size_t)CIN * INTER * sizeof(float));    // 2*256 f32

    transpose_w1<<<(INTER * CIN + 255) / 256, 256, 0, stream>>>(w1, w1t);
    row_kernel<<<BDIM, 256, 0, stream>>>(tea, stu, w1t, bias1, h);
    bn_stats<<<INTER, 256, 0, stream>>>(h, mv);
    bn_out<<<BDIM, 256, 0, stream>>>(h, mv, gamma, beta, w2, b2, out);
}

// Round 3
// 205.393 us; speedup vs baseline: 4.5136x; 1.1293x over previous
//
#include <hip/hip_runtime.h>
#include <hip/hip_bf16.h>
#include <math.h>

#define CDIM  50257
#define BDIM  2048
#define TK    100
#define INTER 256
#define CIN   200
#define NBINS 4096
#define CAP   2048
#define BNEPS 1e-5f
#define THR   2.60f      // static candidate threshold; rank-100 of N(0,1)^50257 ~ 2.88
#define OVF   80.0f      // |x| beyond this risks expf overflow -> fallback

typedef float f32x4 __attribute__((ext_vector_type(4)));

__device__ __forceinline__ unsigned int ordered_bits(float x) {
    unsigned int u = __float_as_uint(x);
    return (u & 0x80000000u) ? ~u : (u | 0x80000000u);
}
__device__ __forceinline__ float inv_ordered(unsigned int o) {
    unsigned int u = (o & 0x80000000u) ? (o & 0x7fffffffu) : ~o;
    return __uint_as_float(u);
}
__device__ __forceinline__ void online1(float x, float& m, float& s) {
    if (x > m) { s = s * __expf(m - x) + 1.f; m = x; }
    else       { s += __expf(x - m); }
}
__device__ __forceinline__ void online4(f32x4 v, float& m, float& s) {
    float m4 = fmaxf(fmaxf(v.x, v.y), fmaxf(v.z, v.w));
    if (m4 > m) { s *= __expf(m - m4); m = m4; }
    s += __expf(v.x - m) + __expf(v.y - m) + __expf(v.z - m) + __expf(v.w - m);
}

// ---------------- kernel 0: transpose conv1_w [256][200] -> w1t [200][256] ----------------
__global__ __launch_bounds__(256) void transpose_w1(const float* __restrict__ w1,
                                                    float* __restrict__ w1t) {
    int o = blockIdx.x * 256 + threadIdx.x;
    if (o < INTER * CIN) {
        int c = o & (INTER - 1);
        int k = o >> 8;
        w1t[o] = w1[c * CIN + k];
    }
}

// ---------------- kernel 1: fused single-pass fast path ----------------
__global__ __launch_bounds__(256, 8) void row_fast(const float* __restrict__ tea,
                                                   const float* __restrict__ stu,
                                                   const float* __restrict__ w1t,
                                                   const float* __restrict__ bias1,
                                                   float* __restrict__ h,
                                                   int* __restrict__ status) {
    __shared__ __align__(16) float cand_x[CAP];
    __shared__ int   cand_i[CAP];
    __shared__ float comb[CIN];
    __shared__ int   sel_idx[TK];
    __shared__ float redA[4], redB[4], redC[4], redD[4];
    __shared__ unsigned int cand_cnt;

    const int tid = threadIdx.x;
    const int row = blockIdx.x;
    const float* trow = tea + (size_t)row * CDIM;
    const float* srow = stu + (size_t)row * CDIM;
    const int pre  = (4 - (row & 3)) & 3;
    const int nv   = (CDIM - pre) >> 2;
    const int tail = pre + (nv << 2);
    const f32x4* tv4 = (const f32x4*)(trow + pre);
    const f32x4* sv4 = (const f32x4*)(srow + pre);

    if (tid == 0) cand_cnt = 0u;
    __syncthreads();

    float sT = 0.f, mT = -INFINITY, sS = 0.f, mS = -INFINITY;

    for (int i = tid; i < pre; i += 256) {
        float x = trow[i], y = srow[i];
        mT = fmaxf(mT, x); sT += __expf(x);
        mS = fmaxf(mS, y); sS += __expf(y);
        if (x >= THR) { unsigned p = atomicAdd(&cand_cnt, 1u); if (p < CAP) { cand_x[p] = x; cand_i[p] = i; } }
    }
    for (int i = tail + tid; i < CDIM; i += 256) {
        float x = trow[i], y = srow[i];
        mT = fmaxf(mT, x); sT += __expf(x);
        mS = fmaxf(mS, y); sS += __expf(y);
        if (x >= THR) { unsigned p = atomicAdd(&cand_cnt, 1u); if (p < CAP) { cand_x[p] = x; cand_i[p] = i; } }
    }
#pragma unroll 2
    for (int k = tid; k < nv; k += 256) {
        f32x4 a = __builtin_nontemporal_load(tv4 + k);
        f32x4 b = __builtin_nontemporal_load(sv4 + k);
        float a4 = fmaxf(fmaxf(a.x, a.y), fmaxf(a.z, a.w));
        float b4 = fmaxf(fmaxf(b.x, b.y), fmaxf(b.z, b.w));
        mT = fmaxf(mT, a4);
        mS = fmaxf(mS, b4);
        sT += (__expf(a.x) + __expf(a.y)) + (__expf(a.z) + __expf(a.w));
        sS += (__expf(b.x) + __expf(b.y)) + (__expf(b.z) + __expf(b.w));
        if (a4 >= THR) {
            int base = pre + (k << 2);
            if (a.x >= THR) { unsigned p = atomicAdd(&cand_cnt, 1u); if (p < CAP) { cand_x[p] = a.x; cand_i[p] = base;     } }
            if (a.y >= THR) { unsigned p = atomicAdd(&cand_cnt, 1u); if (p < CAP) { cand_x[p] = a.y; cand_i[p] = base + 1; } }
            if (a.z >= THR) { unsigned p = atomicAdd(&cand_cnt, 1u); if (p < CAP) { cand_x[p] = a.z; cand_i[p] = base + 2; } }
            if (a.w >= THR) { unsigned p = atomicAdd(&cand_cnt, 1u); if (p < CAP) { cand_x[p] = a.w; cand_i[p] = base + 3; } }
        }
    }
#pragma unroll
    for (int o = 32; o; o >>= 1) {
        sT += __shfl_xor(sT, o, 64);
        sS += __shfl_xor(sS, o, 64);
        mT = fmaxf(mT, __shfl_xor(mT, o, 64));
        mS = fmaxf(mS, __shfl_xor(mS, o, 64));
    }
    if ((tid & 63) == 0) { int w = tid >> 6; redA[w] = sT; redB[w] = sS; redC[w] = mT; redD[w] = mS; }
    __syncthreads();
    const float ST = (redA[0] + redA[1]) + (redA[2] + redA[3]);
    const float SS = (redB[0] + redB[1]) + (redB[2] + redB[3]);
    const float MT = fmaxf(fmaxf(redC[0], redC[1]), fmaxf(redC[2], redC[3]));
    const float MS = fmaxf(fmaxf(redD[0], redD[1]), fmaxf(redD[2], redD[3]));

    const unsigned int cc = cand_cnt;
    const bool bad = (cc < TK) || (cc > CAP) || (MT > OVF) || (MS > OVF);
    if (tid == 0) status[row] = bad ? 1 : 0;
    if (bad) return;          // block-uniform; fixup kernel redoes this row exactly
    const int n = (int)cc;

    // candidates -> softmax probabilities (no max shift: e^x/S == e^(x-M)/S')
    for (int i = tid; i < n; i += 256) cand_x[i] = __expf(cand_x[i]) / ST;
    __syncthreads();

    // exact rank: descending p, ties -> lower index first
    for (int i = tid; i < n; i += 256) {
        float pi = cand_x[i];
        int   ii = cand_i[i];
        int r = 0;
        for (int j = 0; j < n; ++j) {
            float pj = cand_x[j];
            r += (pj > pi) || ((pj == pi) && (cand_i[j] < ii));
        }
        if (r < TK) { comb[r] = pi; sel_idx[r] = ii; }
    }
    __syncthreads();
    if (tid < TK) comb[TK + tid] = __expf(srow[sel_idx[tid]]) / SS;
    __syncthreads();

    float hc = bias1[tid];
#pragma unroll 4
    for (int k = 0; k < CIN; ++k) hc = fmaf(comb[k], w1t[k * INTER + tid], hc);
    h[(size_t)row * INTER + tid] = hc;
}

// ---------------- kernel 2: exact fixup (round-2 histogram algorithm), early-exits when clean ----------------
__global__ __launch_bounds__(256, 8) void row_fixup(const float* __restrict__ tea,
                                                    const float* __restrict__ stu,
                                                    const float* __restrict__ w1t,
                                                    const float* __restrict__ bias1,
                                                    float* __restrict__ h,
                                                    const int* __restrict__ status) {
    const int row = blockIdx.x;
    if (status[row] == 0) return;   // uniform: all threads exit before any barrier

    __shared__ __align__(16) unsigned char pool[NBINS * 4];
    unsigned int* hist   = (unsigned int*)pool;
    float*        cand_x = (float*)pool;
    int*          cand_i = (int*)(pool + CAP * sizeof(float));
    __shared__ unsigned int chunk[256];
    __shared__ float comb[CIN];
    __shared__ int   sel_idx[TK];
    __shared__ float red_a[4], red_b[4];
    __shared__ int   s_bin1;
    __shared__ unsigned int cand_cnt;

    const int tid = threadIdx.x;
    const float* trow = tea + (size_t)row * CDIM;
    const float* srow = stu + (size_t)row * CDIM;
    const int pre  = (4 - (row & 3)) & 3;
    const int nv   = (CDIM - pre) >> 2;
    const int tail = pre + (nv << 2);
    const f32x4* tv4 = (const f32x4*)(trow + pre);
    const f32x4* sv4 = (const f32x4*)(srow + pre);

    for (int i = tid; i < NBINS; i += 256) hist[i] = 0u;
    if (tid == 0) cand_cnt = 0u;
    __syncthreads();

    float m = -INFINITY, s = 0.f;
    for (int i = tid; i < pre; i += 256) {
        float x = trow[i];
        atomicAdd(&hist[ordered_bits(x) >> 20], 1u);
        online1(x, m, s);
    }
    for (int i = tail + tid; i < CDIM; i += 256) {
        float x = trow[i];
        atomicAdd(&hist[ordered_bits(x) >> 20], 1u);
        online1(x, m, s);
    }
    for (int k = tid; k < nv; k += 256) {
        f32x4 v = tv4[k];
        atomicAdd(&hist[ordered_bits(v.x) >> 20], 1u);
        atomicAdd(&hist[ordered_bits(v.y) >> 20], 1u);
        atomicAdd(&hist[ordered_bits(v.z) >> 20], 1u);
        atomicAdd(&hist[ordered_bits(v.w) >> 20], 1u);
        online4(v, m, s);
    }
#pragma unroll
    for (int o = 32; o; o >>= 1) {
        float mo = __shfl_xor(m, o, 64), so = __shfl_xor(s, o, 64);
        float mn = fmaxf(m, mo);
        s = s * __expf(m - mn) + so * __expf(mo - mn);
        m = mn;
    }
    if ((tid & 63) == 0) { red_a[tid >> 6] = m; red_b[tid >> 6] = s; }
    __syncthreads();
    float M = red_a[0], S = red_b[0];
#pragma unroll
    for (int w = 1; w < 4; ++w) {
        float mn = fmaxf(M, red_a[w]);
        S = S * __expf(M - mn) + red_b[w] * __expf(red_a[w] - mn);
        M = mn;
    }

    unsigned int cs = 0;
#pragma unroll
    for (int i = 0; i < NBINS / 256; ++i) cs += hist[tid * (NBINS / 256) + i];
    chunk[tid] = cs;
    __syncthreads();
    if (tid == 0) {
        unsigned int acc = 0;
        int t = 255;
        for (; t > 0; --t) {
            if (acc + chunk[t] >= TK) break;
            acc += chunk[t];
        }
        int b = t * 16;
        for (int i = 15; i >= 0; --i) {
            unsigned int hv = hist[t * 16 + i];
            if (acc + hv >= TK) { b = t * 16 + i; break; }
            acc += hv;
        }
        s_bin1 = b;
    }
    __syncthreads();
    const float thr = inv_ordered(((unsigned int)s_bin1) << 20);

    for (int i = tid; i < pre; i += 256) {
        float x = trow[i];
        if (x >= thr) { unsigned p = atomicAdd(&cand_cnt, 1u); if (p < CAP) { cand_x[p] = x; cand_i[p] = i; } }
    }
    for (int i = tail + tid; i < CDIM; i += 256) {
        float x = trow[i];
        if (x >= thr) { unsigned p = atomicAdd(&cand_cnt, 1u); if (p < CAP) { cand_x[p] = x; cand_i[p] = i; } }
    }
    for (int k = tid; k < nv; k += 256) {
        f32x4 v = tv4[k];
        int base = pre + 4 * k;
        if (v.x >= thr) { unsigned p = atomicAdd(&cand_cnt, 1u); if (p < CAP) { cand_x[p] = v.x; cand_i[p] = base; } }
        if (v.y >= thr) { unsigned p = atomicAdd(&cand_cnt, 1u); if (p < CAP) { cand_x[p] = v.y; cand_i[p] = base + 1; } }
        if (v.z >= thr) { unsigned p = atomicAdd(&cand_cnt, 1u); if (p < CAP) { cand_x[p] = v.z; cand_i[p] = base + 2; } }
        if (v.w >= thr) { unsigned p = atomicAdd(&cand_cnt, 1u); if (p < CAP) { cand_x[p] = v.w; cand_i[p] = base + 3; } }
    }
    __syncthreads();
    int n = (int)cand_cnt; if (n > CAP) n = CAP;

    for (int i = tid; i < n; i += 256) cand_x[i] = __expf(cand_x[i] - M) / S;
    __syncthreads();

    for (int i = tid; i < n; i += 256) {
        float pi = cand_x[i];
        int   ii = cand_i[i];
        int r = 0;
        for (int j = 0; j < n; ++j) {
            float pj = cand_x[j];
            r += (pj > pi) || ((pj == pi) && (cand_i[j] < ii));
        }
        if (r < TK) { comb[r] = pi; sel_idx[r] = ii; }
    }

    float m2 = -INFINITY, s2 = 0.f;
    for (int i = tid; i < pre; i += 256)         online1(srow[i], m2, s2);
    for (int i = tail + tid; i < CDIM; i += 256) online1(srow[i], m2, s2);
    for (int k = tid; k < nv; k += 256)          online4(sv4[k], m2, s2);
#pragma unroll
    for (int o = 32; o; o >>= 1) {
        float mo = __shfl_xor(m2, o, 64), so = __shfl_xor(s2, o, 64);
        float mn = fmaxf(m2, mo);
        s2 = s2 * __expf(m2 - mn) + so * __expf(mo - mn);
        m2 = mn;
    }
    __syncthreads();
    if ((tid & 63) == 0) { red_a[tid >> 6] = m2; red_b[tid >> 6] = s2; }
    __syncthreads();
    float M2 = red_a[0], S2 = red_b[0];
#pragma unroll
    for (int w = 1; w < 4; ++w) {
        float mn = fmaxf(M2, red_a[w]);
        S2 = S2 * __expf(M2 - mn) + red_b[w] * __expf(red_a[w] - mn);
        M2 = mn;
    }

    if (tid < TK) {
        float xg = srow[sel_idx[tid]];
        comb[TK + tid] = __expf(xg - M2) / S2;
    }
    __syncthreads();

    float hc = bias1[tid];
#pragma unroll 4
    for (int k = 0; k < CIN; ++k) hc = fmaf(comb[k], w1t[k * INTER + tid], hc);
    h[(size_t)row * INTER + tid] = hc;
}

// ---------------- kernel 3: batch-norm statistics ----------------
__global__ __launch_bounds__(256) void bn_stats(const float* __restrict__ h,
                                                float* __restrict__ mv) {
    const int c = blockIdx.x, tid = threadIdx.x;
    __shared__ float red[4];
    float v[BDIM / 256];
    float s = 0.f;
#pragma unroll
    for (int r = 0; r < BDIM / 256; ++r) {
        v[r] = h[(size_t)(r * 256 + tid) * INTER + c];
        s += v[r];
    }
#pragma unroll
    for (int o = 32; o; o >>= 1) s += __shfl_xor(s, o, 64);
    if ((tid & 63) == 0) red[tid >> 6] = s;
    __syncthreads();
    const float mu = ((red[0] + red[1]) + (red[2] + red[3])) * (1.f / BDIM);
    __syncthreads();
    float q = 0.f;
#pragma unroll
    for (int r = 0; r < BDIM / 256; ++r) { float d = v[r] - mu; q = fmaf(d, d, q); }
#pragma unroll
    for (int o = 32; o; o >>= 1) q += __shfl_xor(q, o, 64);
    if ((tid & 63) == 0) red[tid >> 6] = q;
    __syncthreads();
    if (tid == 0) {
        mv[c]         = mu;
        mv[INTER + c] = ((red[0] + red[1]) + (red[2] + red[3])) * (1.f / BDIM);
    }
}

// ---------------- kernel 4: BN apply + ReLU + conv2 -> out[row] ----------------
__global__ __launch_bounds__(256) void bn_out(const float* __restrict__ h,
                                              const float* __restrict__ mv,
                                              const float* __restrict__ gamma,
                                              const float* __restrict__ beta,
                                              const float* __restrict__ w2,
                                              const float* __restrict__ b2,
                                              float* __restrict__ out) {
    const int r = blockIdx.x, c = threadIdx.x;
    __shared__ float red[4];
    const float mu  = mv[c];
    const float var = mv[INTER + c];
    const float rs  = 1.0f / sqrtf(var + BNEPS);
    float hv = h[(size_t)r * INTER + c];
    float hn = gamma[c] * (hv - mu) * rs + beta[c];
    hn = fmaxf(hn, 0.f);
    float term = hn * w2[c];
#pragma unroll
    for (int o = 32; o; o >>= 1) term += __shfl_xor(term, o, 64);
    if ((c & 63) == 0) red[c >> 6] = term;
    __syncthreads();
    if (c == 0) out[r] = ((red[0] + red[1]) + (red[2] + red[3])) + b2[0];
}

extern "C" void kernel_launch(void* const* d_in, const int* in_sizes, int n_in,
                              void* d_out, int out_size, void* d_ws, size_t ws_size,
                              hipStream_t stream) {
    const float* tea   = (const float*)d_in[0];
    const float* stu   = (const float*)d_in[1];
    // d_in[2] = lambda_, unused in forward (gradient reversal is identity)
    const float* w1    = (const float*)d_in[3];
    const float* bias1 = (const float*)d_in[4];
    const float* gamma = (const float*)d_in[5];
    const float* beta  = (const float*)d_in[6];
    const float* w2    = (const float*)d_in[7];
    const float* b2    = (const float*)d_in[8];
    float* out = (float*)d_out;

    char* ws = (char*)d_ws;
    size_t off = 0;
    float* h      = (float*)(ws + off); off += (size_t)BDIM * INTER * sizeof(float);
    float* w1t    = (float*)(ws + off); off += (size_t)CIN * INTER * sizeof(float);
    float* mv     = (float*)(ws + off); off += 2 * INTER * sizeof(float);
    int*   status = (int*)(ws + off);

    transpose_w1<<<(INTER * CIN + 255) / 256, 256, 0, stream>>>(w1, w1t);
    row_fast <<<BDIM, 256, 0, stream>>>(tea, stu, w1t, bias1, h, status);
    row_fixup<<<BDIM, 256, 0, stream>>>(tea, stu, w1t, bias1, h, status);
    bn_stats <<<INTER, 256, 0, stream>>>(h, mv);
    bn_out   <<<BDIM, 256, 0, stream>>>(h, mv, gamma, beta, w2, b2, out);
}